// Round 8
// baseline (183.797 us; speedup 1.0000x reference)
//
#include <hip/hip_runtime.h>
#include <hip/hip_bf16.h>
#include <stdint.h>

typedef __attribute__((ext_vector_type(8))) short short8;  // 8 x bf16 MFMA operand
typedef __attribute__((ext_vector_type(4))) float f32x4;   // MFMA accumulator
typedef __attribute__((ext_vector_type(4))) float f32x4v;  // packed 4x f32
typedef __attribute__((ext_vector_type(2))) float f32x2;   // packed 2x f32 (v_pk_fma_f32)

#define DEV static __device__ __forceinline__

// ---- 32-lane (half-wave) sum-reduce via DPP, broadcast to own half ----
DEV float half_red_bcast(float x) {
  int t;
  t = __builtin_amdgcn_update_dpp(0, __float_as_int(x), 0x111, 0xf, 0xf, true); x += __int_as_float(t); // row_shr:1
  t = __builtin_amdgcn_update_dpp(0, __float_as_int(x), 0x112, 0xf, 0xf, true); x += __int_as_float(t); // row_shr:2
  t = __builtin_amdgcn_update_dpp(0, __float_as_int(x), 0x114, 0xf, 0xf, true); x += __int_as_float(t); // row_shr:4
  t = __builtin_amdgcn_update_dpp(0, __float_as_int(x), 0x118, 0xf, 0xf, true); x += __int_as_float(t); // row_shr:8
  t = __builtin_amdgcn_update_dpp(0, __float_as_int(x), 0x142, 0xa, 0xf, true); x += __int_as_float(t); // row_bcast:15 -> rows 1,3
  return __int_as_float(__builtin_amdgcn_ds_swizzle(__float_as_int(x), 0x3E0)); // all <- lane31 of own half
}

DEV void gload16(const void* g, void* lds) {
  __builtin_amdgcn_global_load_lds(
      (const __attribute__((address_space(1))) void*)g,
      (__attribute__((address_space(3))) void*)lds, 16, 0, 0);
}

#define LOG2E 1.44269504088896340736f

// ============================ prep (critical prefix only) =====================
// blocks 0-3: q (in-block) -> wq[h] (pre-scaled by log2(e)); block 0 also
//             zeroes the work-steal counter (runs before segattn in-stream).
// blocks 4+ : segment boundary scan -> starts[B+1]
// The per-head score constant ch = q_h . bk_h cancels (softmax shift-invariance).
__global__ __launch_bounds__(256) void k_prep(
    const float* __restrict__ query, const float* __restrict__ in_w,
    const float* __restrict__ in_b, const int* __restrict__ seg,
    float* __restrict__ wq_ws, int* __restrict__ starts, int* __restrict__ ctr,
    int N, int B)
{
  __shared__ float sh[256];
  int t = threadIdx.x, bid = blockIdx.x;
  if (bid < 4) {
    if (bid == 0 && t == 0) *ctr = 0;           // reset steal counter each launch
    float acc = in_b[t];
    for (int c = 0; c < 256; ++c) acc += query[c] * in_w[t * 256 + c];
    sh[t] = acc * 0.125f;                       // q[t]
    __syncthreads();
    int h = bid;
    float a = 0.f;
    for (int j = 0; j < 64; ++j) a += sh[64 * h + j] * in_w[(256 + 64 * h + j) * 256 + t];
    wq_ws[h * 256 + t] = a * LOG2E;             // exp2-domain
  } else {
    int idx = (bid - 4) * 256 + t;
    if (idx < N) {
      int s = seg[idx];
      int prev = (idx == 0) ? -1 : seg[idx - 1];
      for (int x = prev + 1; x <= s; ++x) starts[x] = idx;
      if (idx == N - 1) for (int x = s + 1; x <= B; ++x) starts[x] = N;
    }
  }
}

// ========== main: per-segment no-max softmax + weighted embedding sum =========
// Blocks [0, 257): input-only mtt/btot precompute (front-placed, hidden under
// the streaming phase). Blocks [257, 257+1024): 4 independent worker waves
// per block; each wave WORK-STEALS segments via a global counter (removes the
// static-assignment straggler tail: max-of-4096 two-segment sums ~92 rows vs
// mean 64). Hot loop: no-max exp2 softmax (scores bounded; shift-invariance
// keeps it exact), f32x2 packed math, 2-deep row prefetch.
__global__ __launch_bounds__(256, 4) void k_segattn(
    const float* __restrict__ emb, const int* __restrict__ starts,
    const float* __restrict__ wq_ws,
    float* __restrict__ mask, __hip_bfloat16* __restrict__ T, int B,
    const float* __restrict__ in_w, const float* __restrict__ in_b,
    const float* __restrict__ Wo, const float* __restrict__ bo,
    const float* __restrict__ Wu, const float* __restrict__ bu,
    __hip_bfloat16* __restrict__ mtt, float* __restrict__ btot,
    int* __restrict__ ctr)
{
  __shared__ float sh[256];
  int t = threadIdx.x;

  if (blockIdx.x < 257u) {
    // ---------------- front blocks: mtt / btot (inputs-only) ----------------
    int bid = blockIdx.x;
    if (bid < 256) {
      int u = bid;
      float wc = 0.f;
      for (int o = 0; o < 256; ++o) wc += Wu[u * 256 + o] * Wo[o * 256 + t];
      sh[t] = wc;                                  // wcomb[u, t]
      __syncthreads();
      #pragma unroll
      for (int h = 0; h < 4; ++h) {
        float a = 0.f;
        for (int r = 0; r < 64; ++r) a += sh[64 * h + r] * in_w[(512 + 64 * h + r) * 256 + t];
        mtt[(size_t)u * 1024 + h * 256 + t] = __float2bfloat16(a);
      }
    } else {
      const float* bv = in_b + 512;
      float wob = 0.f;
      for (int c = 0; c < 256; ++c) wob += Wo[t * 256 + c] * bv[c];
      sh[t] = bo[t] + wob;
      __syncthreads();
      float a = bu[t];
      for (int o = 0; o < 256; ++o) a += Wu[t * 256 + o] * sh[o];
      btot[t] = a;
    }
    return;
  }

  int lane = t & 63;
  int g = lane >> 5, i = lane & 31, i8 = i * 8;

  // per-head weights as 4x f32x2 (packed) — loaded once per wave
  f32x2 w[4][4];
  #pragma unroll
  for (int h = 0; h < 4; ++h) {
    const f32x2* wp = (const f32x2*)(wq_ws + h * 256 + i8);
    #pragma unroll
    for (int j = 0; j < 4; ++j) w[h][j] = wp[j];
  }

  for (;;) {
    // -------- steal next segment (lane 0 atomic, wave-uniform broadcast) ----
    int b0 = 0;
    if (lane == 0) b0 = atomicAdd(ctr, 1);
    int b = __builtin_amdgcn_readfirstlane(b0);
    if (b >= B) break;

    int start = starts[b], end = starts[b + 1];
    __hip_bfloat16* Tb = T + (size_t)b * 1024;

    if (start >= end) {
      if (lane == 0) mask[b] = 0.f;
      if (lane < 32) {
        uint4 z = {0u, 0u, 0u, 0u};
        *(uint4*)(Tb + 0 * 256 + lane * 8) = z;
        *(uint4*)(Tb + 1 * 256 + lane * 8) = z;
        *(uint4*)(Tb + 2 * 256 + lane * 8) = z;
        *(uint4*)(Tb + 3 * 256 + lane * 8) = z;
      }
      continue;
    }
    if (lane == 0) mask[b] = 1.f;

    float d[4] = {0.f, 0.f, 0.f, 0.f};
    f32x2 S[4][4] = {};

    // 2-deep prefetch pipeline
    int r0 = start + g;     if (r0 > end - 1) r0 = end - 1;
    int r1 = start + 2 + g; if (r1 > end - 1) r1 = end - 1;
    const float* p0 = emb + (size_t)r0 * 256 + i8;
    const float* p1 = emb + (size_t)r1 * 256 + i8;
    f32x4v c0 = *(const f32x4v*)p0, c1 = *(const f32x4v*)(p0 + 4);
    f32x4v n10 = *(const f32x4v*)p1, n11 = *(const f32x4v*)(p1 + 4);

    for (int p = start; p < end; p += 2) {
      int rn = p + 4 + g; if (rn > end - 1) rn = end - 1;
      const float* np = emb + (size_t)rn * 256 + i8;
      f32x4v L0 = *(const f32x4v*)np, L1 = *(const f32x4v*)(np + 4);

      f32x2 c0l = __builtin_shufflevector(c0, c0, 0, 1);
      f32x2 c0h = __builtin_shufflevector(c0, c0, 2, 3);
      f32x2 c1l = __builtin_shufflevector(c1, c1, 0, 1);
      f32x2 c1h = __builtin_shufflevector(c1, c1, 2, 3);

      f32x2 P0 = c0l * w[0][0] + c0h * w[0][1] + c1l * w[0][2] + c1h * w[0][3];
      f32x2 P1 = c0l * w[1][0] + c0h * w[1][1] + c1l * w[1][2] + c1h * w[1][3];
      f32x2 P2 = c0l * w[2][0] + c0h * w[2][1] + c1l * w[2][2] + c1h * w[2][3];
      f32x2 P3 = c0l * w[3][0] + c0h * w[3][1] + c1l * w[3][2] + c1h * w[3][3];

      float s0 = half_red_bcast(P0.x + P0.y);
      float s1 = half_red_bcast(P1.x + P1.y);
      float s2 = half_red_bcast(P2.x + P2.y);
      float s3 = half_red_bcast(P3.x + P3.y);

      if ((p + g) >= end) { s0 = -1e30f; s1 = -1e30f; s2 = -1e30f; s3 = -1e30f; }

      float e0 = __builtin_exp2f(s0); d[0] += e0;
      float e1 = __builtin_exp2f(s1); d[1] += e1;
      float e2 = __builtin_exp2f(s2); d[2] += e2;
      float e3 = __builtin_exp2f(s3); d[3] += e3;

#define ACC(h, e)                                                           \
      { f32x2 ev = {e, e};                                                  \
        S[h][0] += ev * c0l; S[h][1] += ev * c0h;                           \
        S[h][2] += ev * c1l; S[h][3] += ev * c1h; }
      ACC(0, e0) ACC(1, e1) ACC(2, e2) ACC(3, e3)
#undef ACC

      c0 = n10; c1 = n11; n10 = L0; n11 = L1;
    }

    // merge halves: d_total = d + other-half d; scale; cross-sum; store bf16
#define FIN(h)                                                              \
    { float od = __shfl_xor(d[h], 32);                                      \
      float sc = 1.f / (d[h] + od);                                         \
      float t0 = S[h][0].x * sc, t1 = S[h][0].y * sc;                       \
      float t2 = S[h][1].x * sc, t3 = S[h][1].y * sc;                       \
      float t4 = S[h][2].x * sc, t5 = S[h][2].y * sc;                       \
      float t6 = S[h][3].x * sc, t7 = S[h][3].y * sc;                       \
      t0 += __shfl_xor(t0, 32); t1 += __shfl_xor(t1, 32);                   \
      t2 += __shfl_xor(t2, 32); t3 += __shfl_xor(t3, 32);                   \
      t4 += __shfl_xor(t4, 32); t5 += __shfl_xor(t5, 32);                   \
      t6 += __shfl_xor(t6, 32); t7 += __shfl_xor(t7, 32);                   \
      if (g == 0) {                                                         \
        union { __hip_bfloat16 v[8]; uint4 u; } pk;                         \
        pk.v[0] = __float2bfloat16(t0); pk.v[1] = __float2bfloat16(t1);     \
        pk.v[2] = __float2bfloat16(t2); pk.v[3] = __float2bfloat16(t3);     \
        pk.v[4] = __float2bfloat16(t4); pk.v[5] = __float2bfloat16(t5);     \
        pk.v[6] = __float2bfloat16(t6); pk.v[7] = __float2bfloat16(t7);     \
        *(uint4*)(Tb + h * 256 + i8) = pk.u; } }
    FIN(0) FIN(1) FIN(2) FIN(3)
#undef FIN
  }
}

// ============ output GEMM: out(B,256) = T(B,1024) @ MtT(256,1024)^T ==========
// bf16 MFMA 16x16x32, 64x64 tile, 4 waves (2x2), XOR-swizzled LDS,
// global_load_lds(width=16) staging with pre-swizzled source addresses.
// Grid (x = M-tile, y = N-tile): blocks sharing a T row-panel are 128 apart
// -> same XCD (128 % 8 == 0) -> T read once per XCD L2.
__global__ __launch_bounds__(256) void k_out(
    const __hip_bfloat16* __restrict__ T, const __hip_bfloat16* __restrict__ mtt,
    const float* __restrict__ btot, const float* __restrict__ mask,
    float* __restrict__ out)
{
  __shared__ __align__(16) char smem[16384];
  char* As = smem;            // [64 rows][128B]
  char* Bs = smem + 8192;
  int t = threadIdx.x;
  int l = t & 63, w = t >> 6;
  int wr = w >> 1, wc = w & 1;
  int tileM = blockIdx.x * 64, tileN = blockIdx.y * 64;

  const char* Tb = (const char*)T;     // row stride 2048 B
  const char* Mb = (const char*)mtt;   // row stride 2048 B
  int chunk = (l & 7) ^ ((l >> 3) & 7);
  f32x4 acc[2][2] = {};

  for (int kk = 0; kk < 1024; kk += 64) {
    #pragma unroll
    for (int i = 0; i < 2; ++i) {
      int row = (w * 2 + i) * 8 + (l >> 3);
      gload16(Tb + (size_t)(tileM + row) * 2048 + kk * 2 + chunk * 16,
              As + (w * 2 + i) * 1024);
      gload16(Mb + (size_t)(tileN + row) * 2048 + kk * 2 + chunk * 16,
              Bs + (w * 2 + i) * 1024);
    }
    __syncthreads();
    #pragma unroll
    for (int ks = 0; ks < 64; ks += 32) {
      short8 a[2], bf[2];
      int kbyte = (ks + (l >> 4) * 8) * 2;
      #pragma unroll
      for (int i = 0; i < 2; ++i) {
        int row = wr * 32 + i * 16 + (l & 15);
        a[i] = *(const short8*)(As + row * 128 + (kbyte ^ ((row & 7) << 4)));
        int crow = wc * 32 + i * 16 + (l & 15);
        bf[i] = *(const short8*)(Bs + crow * 128 + (kbyte ^ ((crow & 7) << 4)));
      }
      #pragma unroll
      for (int i = 0; i < 2; ++i)
        #pragma unroll
        for (int j = 0; j < 2; ++j)
          acc[i][j] = __builtin_amdgcn_mfma_f32_16x16x32_bf16(a[i], bf[j], acc[i][j], 0, 0, 0);
    }
    __syncthreads();
  }

  int cl = l & 15, rq = l >> 4;
  #pragma unroll
  for (int i = 0; i < 2; ++i)
    #pragma unroll
    for (int j = 0; j < 2; ++j) {
      int cg = tileN + wc * 32 + j * 16 + cl;
      float bt = btot[cg];
      #pragma unroll
      for (int r = 0; r < 4; ++r) {
        int rg = tileM + wr * 32 + i * 16 + rq * 4 + r;
        out[(size_t)rg * 256 + cg] = mask[rg] * (acc[i][j][r] + bt);
      }
    }
}

extern "C" void kernel_launch(void* const* d_in, const int* in_sizes, int n_in,
                              void* d_out, int out_size, void* d_ws, size_t ws_size,
                              hipStream_t stream) {
  const float* emb   = (const float*)d_in[0];
  const float* query = (const float*)d_in[1];
  const float* in_w  = (const float*)d_in[2];
  const float* in_b  = (const float*)d_in[3];
  const float* out_w = (const float*)d_in[4];  // Wo
  const float* out_b = (const float*)d_in[5];  // bo
  const float* up_w  = (const float*)d_in[6];  // Wu
  const float* up_b  = (const float*)d_in[7];  // bu
  const int*   seg   = (const int*)d_in[8];

  int N = in_sizes[0] / 256;
  int B = out_size / 256;

  char* wsb = (char*)d_ws;
  float* wq_ws  = (float*)(wsb + 0);        // 1024 f32
  int*   ctr    = (int*)(wsb + 4096);       // work-steal counter
  float* btot   = (float*)(wsb + 8192);     // 256 f32
  int*   starts = (int*)(wsb + 12288);      // B+1 int
  float* maskp  = (float*)(wsb + 45312);    // B f32
  __hip_bfloat16* mtt = (__hip_bfloat16*)(wsb + 78336);   // 256x1024 bf16
  __hip_bfloat16* Tp  = (__hip_bfloat16*)(wsb + 602624);  // B x 1024 bf16

  int nb_bounds = (N + 255) / 256;
  k_prep<<<dim3(4 + nb_bounds), dim3(256), 0, stream>>>(
      query, in_w, in_b, seg, wq_ws, starts, ctr, N, B);
  k_segattn<<<dim3(257 + 1024), dim3(256), 0, stream>>>(
      emb, starts, wq_ws, maskp, Tp, B,
      in_w, in_b, out_w, out_b, up_w, up_b, mtt, btot, ctr);
  k_out<<<dim3(B / 64, 4), dim3(256), 0, stream>>>(Tp, mtt, btot, maskp, (float*)d_out);
}

// Round 9
// 93.987 us; speedup vs baseline: 1.9555x; 1.9555x over previous
//
#include <hip/hip_runtime.h>
#include <hip/hip_bf16.h>
#include <stdint.h>

typedef __attribute__((ext_vector_type(8))) short short8;  // 8 x bf16 MFMA operand
typedef __attribute__((ext_vector_type(4))) float f32x4;   // MFMA accumulator
typedef __attribute__((ext_vector_type(4))) float f32x4v;  // packed 4x f32
typedef __attribute__((ext_vector_type(2))) float f32x2;   // packed 2x f32 (v_pk_fma_f32)

#define DEV static __device__ __forceinline__

// ---- 32-lane (half-wave) sum-reduce via DPP, broadcast to own half ----
DEV float half_red_bcast(float x) {
  int t;
  t = __builtin_amdgcn_update_dpp(0, __float_as_int(x), 0x111, 0xf, 0xf, true); x += __int_as_float(t); // row_shr:1
  t = __builtin_amdgcn_update_dpp(0, __float_as_int(x), 0x112, 0xf, 0xf, true); x += __int_as_float(t); // row_shr:2
  t = __builtin_amdgcn_update_dpp(0, __float_as_int(x), 0x114, 0xf, 0xf, true); x += __int_as_float(t); // row_shr:4
  t = __builtin_amdgcn_update_dpp(0, __float_as_int(x), 0x118, 0xf, 0xf, true); x += __int_as_float(t); // row_shr:8
  t = __builtin_amdgcn_update_dpp(0, __float_as_int(x), 0x142, 0xa, 0xf, true); x += __int_as_float(t); // row_bcast:15 -> rows 1,3
  return __int_as_float(__builtin_amdgcn_ds_swizzle(__float_as_int(x), 0x3E0)); // all <- lane31 of own half
}

DEV void gload16(const void* g, void* lds) {
  __builtin_amdgcn_global_load_lds(
      (const __attribute__((address_space(1))) void*)g,
      (__attribute__((address_space(3))) void*)lds, 16, 0, 0);
}

#define LOG2E 1.44269504088896340736f

// ============================ prep (critical prefix only) =====================
// blocks 0-3: q (in-block) -> wq[h] (pre-scaled by log2(e))
// blocks 4+ : segment boundary scan -> starts[B+1]
// The per-head score constant ch = q_h . bk_h cancels (softmax shift-invariance).
__global__ __launch_bounds__(256) void k_prep(
    const float* __restrict__ query, const float* __restrict__ in_w,
    const float* __restrict__ in_b, const int* __restrict__ seg,
    float* __restrict__ wq_ws, int* __restrict__ starts, int N, int B)
{
  __shared__ float sh[256];
  int t = threadIdx.x, bid = blockIdx.x;
  if (bid < 4) {
    float acc = in_b[t];
    for (int c = 0; c < 256; ++c) acc += query[c] * in_w[t * 256 + c];
    sh[t] = acc * 0.125f;                       // q[t]
    __syncthreads();
    int h = bid;
    float a = 0.f;
    for (int j = 0; j < 64; ++j) a += sh[64 * h + j] * in_w[(256 + 64 * h + j) * 256 + t];
    wq_ws[h * 256 + t] = a * LOG2E;             // exp2-domain
  } else {
    int idx = (bid - 4) * 256 + t;
    if (idx < N) {
      int s = seg[idx];
      int prev = (idx == 0) ? -1 : seg[idx - 1];
      for (int x = prev + 1; x <= s; ++x) starts[x] = idx;
      if (idx == N - 1) for (int x = s + 1; x <= B; ++x) starts[x] = N;
    }
  }
}

// ========== main: per-segment no-max softmax + weighted embedding sum =========
// Blocks [0, 257): input-only mtt/btot precompute (front-placed, hidden).
// Blocks [257, 257+B): ONE BLOCK (4 waves) PER SEGMENT — each wave takes a
// contiguous quarter of the rows (serial chain cut 4x vs one-wave-per-segment,
// shrinking the latency-bound end-game tail), then a block-level LDS merge of
// the 16 partial (d, S) states. Hot loop: no-max exp2 softmax (scores bounded;
// shift-invariance keeps it exact), f32x2 packed math, 2-deep row prefetch.
__global__ __launch_bounds__(256, 4) void k_segattn(
    const float* __restrict__ emb, const int* __restrict__ starts,
    const float* __restrict__ wq_ws,
    float* __restrict__ mask, __hip_bfloat16* __restrict__ T, int B,
    const float* __restrict__ in_w, const float* __restrict__ in_b,
    const float* __restrict__ Wo, const float* __restrict__ bo,
    const float* __restrict__ Wu, const float* __restrict__ bu,
    __hip_bfloat16* __restrict__ mtt, float* __restrict__ btot)
{
  __shared__ float sm[16][256];   // [wave*4+head][dim] partial numerators
  __shared__ float sd[16];        // [wave*4+head] partial denominators
  int t = threadIdx.x;

  if (blockIdx.x < 257u) {
    // ---------------- front blocks: mtt / btot (inputs-only) ----------------
    float* sh = sm[0];
    int bid = blockIdx.x;
    if (bid < 256) {
      int u = bid;
      float wc = 0.f;
      for (int o = 0; o < 256; ++o) wc += Wu[u * 256 + o] * Wo[o * 256 + t];
      sh[t] = wc;                                  // wcomb[u, t]
      __syncthreads();
      #pragma unroll
      for (int h = 0; h < 4; ++h) {
        float a = 0.f;
        for (int r = 0; r < 64; ++r) a += sh[64 * h + r] * in_w[(512 + 64 * h + r) * 256 + t];
        mtt[(size_t)u * 1024 + h * 256 + t] = __float2bfloat16(a);
      }
    } else {
      const float* bv = in_b + 512;
      float wob = 0.f;
      for (int c = 0; c < 256; ++c) wob += Wo[t * 256 + c] * bv[c];
      sh[t] = bo[t] + wob;
      __syncthreads();
      float a = bu[t];
      for (int o = 0; o < 256; ++o) a += Wu[t * 256 + o] * sh[o];
      btot[t] = a;
    }
    return;
  }

  int b = blockIdx.x - 257;
  int start = starts[b], end = starts[b + 1];
  __hip_bfloat16* Tb = T + (size_t)b * 1024;

  if (start >= end) {
    if (t == 0) mask[b] = 0.f;
    if (t < 128) { uint4 z = {0u,0u,0u,0u}; *(uint4*)((char*)Tb + t * 16) = z; }
    return;
  }
  if (t == 0) mask[b] = 1.f;

  int w = t >> 6;                 // wave id: owns rows [ws, we)
  int lane = t & 63;
  int g = lane >> 5, i = lane & 31, i8 = i * 8;

  int len = end - start;
  int per = (len + 3) >> 2;
  int ws = start + w * per;
  int we = ws + per; if (we > end) we = end;

  // per-head weights as 4x f32x2 (packed)
  f32x2 wq[4][4];
  #pragma unroll
  for (int h = 0; h < 4; ++h) {
    const f32x2* wp = (const f32x2*)(wq_ws + h * 256 + i8);
    #pragma unroll
    for (int j = 0; j < 4; ++j) wq[h][j] = wp[j];
  }

  float d[4] = {0.f, 0.f, 0.f, 0.f};
  f32x2 S[4][4] = {};

  if (ws < we) {
    // 2-deep prefetch pipeline over this wave's chunk
    int r0 = ws + g;     if (r0 > we - 1) r0 = we - 1;
    int r1 = ws + 2 + g; if (r1 > we - 1) r1 = we - 1;
    const float* p0 = emb + (size_t)r0 * 256 + i8;
    const float* p1 = emb + (size_t)r1 * 256 + i8;
    f32x4v c0 = *(const f32x4v*)p0, c1 = *(const f32x4v*)(p0 + 4);
    f32x4v n10 = *(const f32x4v*)p1, n11 = *(const f32x4v*)(p1 + 4);

    for (int p = ws; p < we; p += 2) {
      int rn = p + 4 + g; if (rn > we - 1) rn = we - 1;
      const float* np = emb + (size_t)rn * 256 + i8;
      f32x4v L0 = *(const f32x4v*)np, L1 = *(const f32x4v*)(np + 4);

      f32x2 c0l = __builtin_shufflevector(c0, c0, 0, 1);
      f32x2 c0h = __builtin_shufflevector(c0, c0, 2, 3);
      f32x2 c1l = __builtin_shufflevector(c1, c1, 0, 1);
      f32x2 c1h = __builtin_shufflevector(c1, c1, 2, 3);

      f32x2 P0 = c0l * wq[0][0] + c0h * wq[0][1] + c1l * wq[0][2] + c1h * wq[0][3];
      f32x2 P1 = c0l * wq[1][0] + c0h * wq[1][1] + c1l * wq[1][2] + c1h * wq[1][3];
      f32x2 P2 = c0l * wq[2][0] + c0h * wq[2][1] + c1l * wq[2][2] + c1h * wq[2][3];
      f32x2 P3 = c0l * wq[3][0] + c0h * wq[3][1] + c1l * wq[3][2] + c1h * wq[3][3];

      float s0 = half_red_bcast(P0.x + P0.y);
      float s1 = half_red_bcast(P1.x + P1.y);
      float s2 = half_red_bcast(P2.x + P2.y);
      float s3 = half_red_bcast(P3.x + P3.y);

      if ((p + g) >= we) { s0 = -1e30f; s1 = -1e30f; s2 = -1e30f; s3 = -1e30f; }

      float e0 = __builtin_exp2f(s0); d[0] += e0;
      float e1 = __builtin_exp2f(s1); d[1] += e1;
      float e2 = __builtin_exp2f(s2); d[2] += e2;
      float e3 = __builtin_exp2f(s3); d[3] += e3;

#define ACC(h, e)                                                           \
      { f32x2 ev = {e, e};                                                  \
        S[h][0] += ev * c0l; S[h][1] += ev * c0h;                           \
        S[h][2] += ev * c1l; S[h][3] += ev * c1h; }
      ACC(0, e0) ACC(1, e1) ACC(2, e2) ACC(3, e3)
#undef ACC

      c0 = n10; c1 = n11; n10 = L0; n11 = L1;
    }
  }

  // in-wave half merge (raw sums, no normalize), then publish to LDS
#define PUB(h)                                                              \
  { float od = __shfl_xor(d[h], 32);                                        \
    float dt = d[h] + od;                                                   \
    float t0 = S[h][0].x, t1 = S[h][0].y, t2 = S[h][1].x, t3 = S[h][1].y;   \
    float t4 = S[h][2].x, t5 = S[h][2].y, t6 = S[h][3].x, t7 = S[h][3].y;   \
    t0 += __shfl_xor(t0, 32); t1 += __shfl_xor(t1, 32);                     \
    t2 += __shfl_xor(t2, 32); t3 += __shfl_xor(t3, 32);                     \
    t4 += __shfl_xor(t4, 32); t5 += __shfl_xor(t5, 32);                     \
    t6 += __shfl_xor(t6, 32); t7 += __shfl_xor(t7, 32);                     \
    if (g == 0) {                                                           \
      float* row = sm[w * 4 + h];                                           \
      f32x4v v0 = {t0, t1, t2, t3}, v1 = {t4, t5, t6, t7};                  \
      *(f32x4v*)(row + i8) = v0; *(f32x4v*)(row + i8 + 4) = v1;             \
      if (i == 0) sd[w * 4 + h] = dt; } }
  PUB(0) PUB(1) PUB(2) PUB(3)
#undef PUB

  __syncthreads();

  // block merge: thread t handles dim t for all 4 heads
  #pragma unroll
  for (int h = 0; h < 4; ++h) {
    float den = sd[h] + sd[4 + h] + sd[8 + h] + sd[12 + h];
    float num = sm[h][t] + sm[4 + h][t] + sm[8 + h][t] + sm[12 + h][t];
    Tb[h * 256 + t] = __float2bfloat16(num / den);
  }
}

// ============ output GEMM: out(B,256) = T(B,1024) @ MtT(256,1024)^T ==========
// bf16 MFMA 16x16x32, 64x64 tile, 4 waves (2x2), XOR-swizzled LDS,
// global_load_lds(width=16) staging with pre-swizzled source addresses.
// Grid (x = M-tile, y = N-tile): blocks sharing a T row-panel are 128 apart
// -> same XCD (128 % 8 == 0) -> T read once per XCD L2.
__global__ __launch_bounds__(256) void k_out(
    const __hip_bfloat16* __restrict__ T, const __hip_bfloat16* __restrict__ mtt,
    const float* __restrict__ btot, const float* __restrict__ mask,
    float* __restrict__ out)
{
  __shared__ __align__(16) char smem[16384];
  char* As = smem;            // [64 rows][128B]
  char* Bs = smem + 8192;
  int t = threadIdx.x;
  int l = t & 63, w = t >> 6;
  int wr = w >> 1, wc = w & 1;
  int tileM = blockIdx.x * 64, tileN = blockIdx.y * 64;

  const char* Tb = (const char*)T;     // row stride 2048 B
  const char* Mb = (const char*)mtt;   // row stride 2048 B
  int chunk = (l & 7) ^ ((l >> 3) & 7);
  f32x4 acc[2][2] = {};

  for (int kk = 0; kk < 1024; kk += 64) {
    #pragma unroll
    for (int i = 0; i < 2; ++i) {
      int row = (w * 2 + i) * 8 + (l >> 3);
      gload16(Tb + (size_t)(tileM + row) * 2048 + kk * 2 + chunk * 16,
              As + (w * 2 + i) * 1024);
      gload16(Mb + (size_t)(tileN + row) * 2048 + kk * 2 + chunk * 16,
              Bs + (w * 2 + i) * 1024);
    }
    __syncthreads();
    #pragma unroll
    for (int ks = 0; ks < 64; ks += 32) {
      short8 a[2], bf[2];
      int kbyte = (ks + (l >> 4) * 8) * 2;
      #pragma unroll
      for (int i = 0; i < 2; ++i) {
        int row = wr * 32 + i * 16 + (l & 15);
        a[i] = *(const short8*)(As + row * 128 + (kbyte ^ ((row & 7) << 4)));
        int crow = wc * 32 + i * 16 + (l & 15);
        bf[i] = *(const short8*)(Bs + crow * 128 + (kbyte ^ ((crow & 7) << 4)));
      }
      #pragma unroll
      for (int i = 0; i < 2; ++i)
        #pragma unroll
        for (int j = 0; j < 2; ++j)
          acc[i][j] = __builtin_amdgcn_mfma_f32_16x16x32_bf16(a[i], bf[j], acc[i][j], 0, 0, 0);
    }
    __syncthreads();
  }

  int cl = l & 15, rq = l >> 4;
  #pragma unroll
  for (int i = 0; i < 2; ++i)
    #pragma unroll
    for (int j = 0; j < 2; ++j) {
      int cg = tileN + wc * 32 + j * 16 + cl;
      float bt = btot[cg];
      #pragma unroll
      for (int r = 0; r < 4; ++r) {
        int rg = tileM + wr * 32 + i * 16 + rq * 4 + r;
        out[(size_t)rg * 256 + cg] = mask[rg] * (acc[i][j][r] + bt);
      }
    }
}

extern "C" void kernel_launch(void* const* d_in, const int* in_sizes, int n_in,
                              void* d_out, int out_size, void* d_ws, size_t ws_size,
                              hipStream_t stream) {
  const float* emb   = (const float*)d_in[0];
  const float* query = (const float*)d_in[1];
  const float* in_w  = (const float*)d_in[2];
  const float* in_b  = (const float*)d_in[3];
  const float* out_w = (const float*)d_in[4];  // Wo
  const float* out_b = (const float*)d_in[5];  // bo
  const float* up_w  = (const float*)d_in[6];  // Wu
  const float* up_b  = (const float*)d_in[7];  // bu
  const int*   seg   = (const int*)d_in[8];

  int N = in_sizes[0] / 256;
  int B = out_size / 256;

  char* wsb = (char*)d_ws;
  float* wq_ws  = (float*)(wsb + 0);        // 1024 f32
  float* btot   = (float*)(wsb + 8192);     // 256 f32
  int*   starts = (int*)(wsb + 12288);      // B+1 int
  float* maskp  = (float*)(wsb + 45312);    // B f32
  __hip_bfloat16* mtt = (__hip_bfloat16*)(wsb + 78336);   // 256x1024 bf16
  __hip_bfloat16* Tp  = (__hip_bfloat16*)(wsb + 602624);  // B x 1024 bf16

  int nb_bounds = (N + 255) / 256;
  k_prep<<<dim3(4 + nb_bounds), dim3(256), 0, stream>>>(
      query, in_w, in_b, seg, wq_ws, starts, N, B);
  k_segattn<<<dim3(257 + B), dim3(256), 0, stream>>>(
      emb, starts, wq_ws, maskp, Tp, B,
      in_w, in_b, out_w, out_b, up_w, up_b, mtt, btot);
  k_out<<<dim3(B / 64, 4), dim3(256), 0, stream>>>(Tp, mtt, btot, maskp, (float*)d_out);
}

// Round 10
// 82.122 us; speedup vs baseline: 2.2381x; 1.1445x over previous
//
#include <hip/hip_runtime.h>
#include <hip/hip_bf16.h>
#include <stdint.h>

typedef __attribute__((ext_vector_type(8))) short short8;  // 8 x bf16 MFMA operand
typedef __attribute__((ext_vector_type(4))) float f32x4;   // MFMA accumulator
typedef __attribute__((ext_vector_type(4))) float f32x4v;  // packed 4x f32
typedef __attribute__((ext_vector_type(2))) float f32x2;   // packed 2x f32 (v_pk_fma_f32)

#define DEV static __device__ __forceinline__

// ---- 32-lane (half-wave) sum-reduce via DPP, broadcast to own half ----
DEV float half_red_bcast(float x) {
  int t;
  t = __builtin_amdgcn_update_dpp(0, __float_as_int(x), 0x111, 0xf, 0xf, true); x += __int_as_float(t); // row_shr:1
  t = __builtin_amdgcn_update_dpp(0, __float_as_int(x), 0x112, 0xf, 0xf, true); x += __int_as_float(t); // row_shr:2
  t = __builtin_amdgcn_update_dpp(0, __float_as_int(x), 0x114, 0xf, 0xf, true); x += __int_as_float(t); // row_shr:4
  t = __builtin_amdgcn_update_dpp(0, __float_as_int(x), 0x118, 0xf, 0xf, true); x += __int_as_float(t); // row_shr:8
  t = __builtin_amdgcn_update_dpp(0, __float_as_int(x), 0x142, 0xa, 0xf, true); x += __int_as_float(t); // row_bcast:15 -> rows 1,3
  return __int_as_float(__builtin_amdgcn_ds_swizzle(__float_as_int(x), 0x3E0)); // all <- lane31 of own half
}

DEV void gload16(const void* g, void* lds) {
  __builtin_amdgcn_global_load_lds(
      (const __attribute__((address_space(1))) void*)g,
      (__attribute__((address_space(3))) void*)lds, 16, 0, 0);
}

#define LOG2E 1.44269504088896340736f

// ============================ prep (critical prefix only) =====================
// blocks 0-3: q (in-block) -> wq[h] (pre-scaled by log2(e))
// blocks 4+ : segment boundary scan -> starts[B+1]
// The per-head score constant ch = q_h . bk_h cancels (softmax shift-invariance).
__global__ __launch_bounds__(256) void k_prep(
    const float* __restrict__ query, const float* __restrict__ in_w,
    const float* __restrict__ in_b, const int* __restrict__ seg,
    float* __restrict__ wq_ws, int* __restrict__ starts, int N, int B)
{
  __shared__ float sh[256];
  int t = threadIdx.x, bid = blockIdx.x;
  if (bid < 4) {
    float acc = in_b[t];
    for (int c = 0; c < 256; ++c) acc += query[c] * in_w[t * 256 + c];
    sh[t] = acc * 0.125f;                       // q[t]
    __syncthreads();
    int h = bid;
    float a = 0.f;
    for (int j = 0; j < 64; ++j) a += sh[64 * h + j] * in_w[(256 + 64 * h + j) * 256 + t];
    wq_ws[h * 256 + t] = a * LOG2E;             // exp2-domain
  } else {
    int idx = (bid - 4) * 256 + t;
    if (idx < N) {
      int s = seg[idx];
      int prev = (idx == 0) ? -1 : seg[idx - 1];
      for (int x = prev + 1; x <= s; ++x) starts[x] = idx;
      if (idx == N - 1) for (int x = s + 1; x <= B; ++x) starts[x] = N;
    }
  }
}

// ========== main: per-segment no-max softmax + weighted embedding sum =========
// (R6 proven structure, byte-identical.) Blocks [0, 257): input-only mtt/btot
// precompute, front-placed so they hide under the streaming phase. Blocks
// [257, 257+nB): 4 waves/block, ONE WAVE PER SEGMENT; each 32-lane half owns
// one node/iter (8 dims/lane, f32x2 packed); no-max exp2 softmax (scores
// bounded; shift-invariance exact); 2-deep row prefetch. VGPR must stay <=64
// (occupancy cliff at 64 -> 32 waves/CU).
__global__ __launch_bounds__(256, 4) void k_segattn(
    const float* __restrict__ emb, const int* __restrict__ starts,
    const float* __restrict__ wq_ws,
    float* __restrict__ mask, __hip_bfloat16* __restrict__ T, int B,
    const float* __restrict__ in_w, const float* __restrict__ in_b,
    const float* __restrict__ Wo, const float* __restrict__ bo,
    const float* __restrict__ Wu, const float* __restrict__ bu,
    __hip_bfloat16* __restrict__ mtt, float* __restrict__ btot)
{
  __shared__ float sh[256];
  int t = threadIdx.x;

  if (blockIdx.x < 257u) {
    // ---------------- front blocks: mtt / btot (inputs-only) ----------------
    int bid = blockIdx.x;
    if (bid < 256) {
      int u = bid;
      float wc = 0.f;
      for (int o = 0; o < 256; ++o) wc += Wu[u * 256 + o] * Wo[o * 256 + t];
      sh[t] = wc;                                  // wcomb[u, t]
      __syncthreads();
      #pragma unroll
      for (int h = 0; h < 4; ++h) {
        float a = 0.f;
        for (int r = 0; r < 64; ++r) a += sh[64 * h + r] * in_w[(512 + 64 * h + r) * 256 + t];
        mtt[(size_t)u * 1024 + h * 256 + t] = __float2bfloat16(a);
      }
    } else {
      const float* bv = in_b + 512;
      float wob = 0.f;
      for (int c = 0; c < 256; ++c) wob += Wo[t * 256 + c] * bv[c];
      sh[t] = bo[t] + wob;
      __syncthreads();
      float a = bu[t];
      for (int o = 0; o < 256; ++o) a += Wu[t * 256 + o] * sh[o];
      btot[t] = a;
    }
    return;
  }

  int lane = t & 63;
  int g = lane >> 5, i = lane & 31, i8 = i * 8;
  int b = (blockIdx.x - 257) * 4 + (t >> 6);
  if (b >= B) return;
  int start = starts[b], end = starts[b + 1];
  __hip_bfloat16* Tb = T + (size_t)b * 1024;

  if (start >= end) {
    if (lane == 0) mask[b] = 0.f;
    if (lane < 32) {
      uint4 z = {0u, 0u, 0u, 0u};
      *(uint4*)(Tb + 0 * 256 + lane * 8) = z;
      *(uint4*)(Tb + 1 * 256 + lane * 8) = z;
      *(uint4*)(Tb + 2 * 256 + lane * 8) = z;
      *(uint4*)(Tb + 3 * 256 + lane * 8) = z;
    }
    return;
  }
  if (lane == 0) mask[b] = 1.f;

  // per-head weights as 4x f32x2 (packed)
  f32x2 w[4][4];
  #pragma unroll
  for (int h = 0; h < 4; ++h) {
    const f32x2* wp = (const f32x2*)(wq_ws + h * 256 + i8);
    #pragma unroll
    for (int j = 0; j < 4; ++j) w[h][j] = wp[j];
  }

  float d[4] = {0.f, 0.f, 0.f, 0.f};
  f32x2 S[4][4] = {};

  // 2-deep prefetch pipeline
  int r0 = start + g;     if (r0 > end - 1) r0 = end - 1;
  int r1 = start + 2 + g; if (r1 > end - 1) r1 = end - 1;
  const float* p0 = emb + (size_t)r0 * 256 + i8;
  const float* p1 = emb + (size_t)r1 * 256 + i8;
  f32x4v c0 = *(const f32x4v*)p0, c1 = *(const f32x4v*)(p0 + 4);
  f32x4v n10 = *(const f32x4v*)p1, n11 = *(const f32x4v*)(p1 + 4);

  for (int p = start; p < end; p += 2) {
    int rn = p + 4 + g; if (rn > end - 1) rn = end - 1;
    const float* np = emb + (size_t)rn * 256 + i8;
    f32x4v L0 = *(const f32x4v*)np, L1 = *(const f32x4v*)(np + 4);

    f32x2 c0l = __builtin_shufflevector(c0, c0, 0, 1);
    f32x2 c0h = __builtin_shufflevector(c0, c0, 2, 3);
    f32x2 c1l = __builtin_shufflevector(c1, c1, 0, 1);
    f32x2 c1h = __builtin_shufflevector(c1, c1, 2, 3);

    f32x2 P0 = c0l * w[0][0] + c0h * w[0][1] + c1l * w[0][2] + c1h * w[0][3];
    f32x2 P1 = c0l * w[1][0] + c0h * w[1][1] + c1l * w[1][2] + c1h * w[1][3];
    f32x2 P2 = c0l * w[2][0] + c0h * w[2][1] + c1l * w[2][2] + c1h * w[2][3];
    f32x2 P3 = c0l * w[3][0] + c0h * w[3][1] + c1l * w[3][2] + c1h * w[3][3];

    float s0 = half_red_bcast(P0.x + P0.y);
    float s1 = half_red_bcast(P1.x + P1.y);
    float s2 = half_red_bcast(P2.x + P2.y);
    float s3 = half_red_bcast(P3.x + P3.y);

    if ((p + g) >= end) { s0 = -1e30f; s1 = -1e30f; s2 = -1e30f; s3 = -1e30f; }

    float e0 = __builtin_exp2f(s0); d[0] += e0;
    float e1 = __builtin_exp2f(s1); d[1] += e1;
    float e2 = __builtin_exp2f(s2); d[2] += e2;
    float e3 = __builtin_exp2f(s3); d[3] += e3;

#define ACC(h, e)                                                           \
    { f32x2 ev = {e, e};                                                    \
      S[h][0] += ev * c0l; S[h][1] += ev * c0h;                             \
      S[h][2] += ev * c1l; S[h][3] += ev * c1h; }
    ACC(0, e0) ACC(1, e1) ACC(2, e2) ACC(3, e3)
#undef ACC

    c0 = n10; c1 = n11; n10 = L0; n11 = L1;
  }

  // merge halves: d_total = d + other-half d; scale; cross-sum; store bf16
#define FIN(h)                                                              \
  { float od = __shfl_xor(d[h], 32);                                        \
    float sc = 1.f / (d[h] + od);                                           \
    float t0 = S[h][0].x * sc, t1 = S[h][0].y * sc;                         \
    float t2 = S[h][1].x * sc, t3 = S[h][1].y * sc;                         \
    float t4 = S[h][2].x * sc, t5 = S[h][2].y * sc;                         \
    float t6 = S[h][3].x * sc, t7 = S[h][3].y * sc;                         \
    t0 += __shfl_xor(t0, 32); t1 += __shfl_xor(t1, 32);                     \
    t2 += __shfl_xor(t2, 32); t3 += __shfl_xor(t3, 32);                     \
    t4 += __shfl_xor(t4, 32); t5 += __shfl_xor(t5, 32);                     \
    t6 += __shfl_xor(t6, 32); t7 += __shfl_xor(t7, 32);                     \
    if (g == 0) {                                                           \
      union { __hip_bfloat16 v[8]; uint4 u; } pk;                           \
      pk.v[0] = __float2bfloat16(t0); pk.v[1] = __float2bfloat16(t1);       \
      pk.v[2] = __float2bfloat16(t2); pk.v[3] = __float2bfloat16(t3);       \
      pk.v[4] = __float2bfloat16(t4); pk.v[5] = __float2bfloat16(t5);       \
      pk.v[6] = __float2bfloat16(t6); pk.v[7] = __float2bfloat16(t7);       \
      *(uint4*)(Tb + h * 256 + i8) = pk.u; } }
  FIN(0) FIN(1) FIN(2) FIN(3)
#undef FIN
}

// ============ output GEMM: out(B,256) = T(B,1024) @ MtT(256,1024)^T ==========
// bf16 MFMA 16x16x32, 64x64 tile, 4 waves (2x2), XOR-swizzled LDS,
// global_load_lds(width=16), DOUBLE-BUFFERED 2-phase: stage(t+1) issued
// BEFORE compute(t), one barrier per K-step (T3 minimum). Grid transposed
// (x = M-tile): row-panel partners 128 apart -> same XCD -> T L2 reuse.
__global__ __launch_bounds__(256) void k_out(
    const __hip_bfloat16* __restrict__ T, const __hip_bfloat16* __restrict__ mtt,
    const float* __restrict__ btot, const float* __restrict__ mask,
    float* __restrict__ out)
{
  __shared__ __align__(16) char smem[32768];   // [buf 16KB][A 8KB | B 8KB]
  int t = threadIdx.x;
  int l = t & 63, w = t >> 6;
  int wr = w >> 1, wc = w & 1;
  int tileM = blockIdx.x * 64, tileN = blockIdx.y * 64;

  const char* Tb = (const char*)T;     // row stride 2048 B
  const char* Mb = (const char*)mtt;   // row stride 2048 B
  int chunk = (l & 7) ^ ((l >> 3) & 7);      // inverse-swizzled source chunk

  const char* aSrc[2]; const char* bSrc[2]; int ldsOff[2];
  #pragma unroll
  for (int i = 0; i < 2; ++i) {
    int row = (w * 2 + i) * 8 + (l >> 3);
    aSrc[i] = Tb + (size_t)(tileM + row) * 2048 + chunk * 16;
    bSrc[i] = Mb + (size_t)(tileN + row) * 2048 + chunk * 16;
    ldsOff[i] = (w * 2 + i) * 1024;
  }

  f32x4 acc[2][2] = {};

#define STAGE(step, base)                                                   \
  { int kb = (step) * 128;                                                  \
    _Pragma("unroll")                                                       \
    for (int i = 0; i < 2; ++i) {                                           \
      gload16(aSrc[i] + kb, smem + (base) + ldsOff[i]);                     \
      gload16(bSrc[i] + kb, smem + (base) + 8192 + ldsOff[i]);              \
    } }

  STAGE(0, 0);
  __syncthreads();

  int dbuf = 0;
  for (int step = 0; step < 16; ++step) {
    int base = dbuf << 14;
    if (step + 1 < 16) STAGE(step + 1, base ^ 16384);
    const char* As = smem + base;
    const char* Bs = smem + base + 8192;
    #pragma unroll
    for (int ks = 0; ks < 64; ks += 32) {
      short8 a[2], bf[2];
      int kbyte = (ks + (l >> 4) * 8) * 2;
      #pragma unroll
      for (int i = 0; i < 2; ++i) {
        int row = wr * 32 + i * 16 + (l & 15);
        a[i] = *(const short8*)(As + row * 128 + (kbyte ^ ((row & 7) << 4)));
        int crow = wc * 32 + i * 16 + (l & 15);
        bf[i] = *(const short8*)(Bs + crow * 128 + (kbyte ^ ((crow & 7) << 4)));
      }
      #pragma unroll
      for (int i = 0; i < 2; ++i)
        #pragma unroll
        for (int j = 0; j < 2; ++j)
          acc[i][j] = __builtin_amdgcn_mfma_f32_16x16x32_bf16(a[i], bf[j], acc[i][j], 0, 0, 0);
    }
    __syncthreads();   // drains stage(t+1) vmcnt + protects buf reuse
    dbuf ^= 1;
  }
#undef STAGE

  int cl = l & 15, rq = l >> 4;
  #pragma unroll
  for (int i = 0; i < 2; ++i)
    #pragma unroll
    for (int j = 0; j < 2; ++j) {
      int cg = tileN + wc * 32 + j * 16 + cl;
      float bt = btot[cg];
      #pragma unroll
      for (int r = 0; r < 4; ++r) {
        int rg = tileM + wr * 32 + i * 16 + rq * 4 + r;
        out[(size_t)rg * 256 + cg] = mask[rg] * (acc[i][j][r] + bt);
      }
    }
}

extern "C" void kernel_launch(void* const* d_in, const int* in_sizes, int n_in,
                              void* d_out, int out_size, void* d_ws, size_t ws_size,
                              hipStream_t stream) {
  const float* emb   = (const float*)d_in[0];
  const float* query = (const float*)d_in[1];
  const float* in_w  = (const float*)d_in[2];
  const float* in_b  = (const float*)d_in[3];
  const float* out_w = (const float*)d_in[4];  // Wo
  const float* out_b = (const float*)d_in[5];  // bo
  const float* up_w  = (const float*)d_in[6];  // Wu
  const float* up_b  = (const float*)d_in[7];  // bu
  const int*   seg   = (const int*)d_in[8];

  int N = in_sizes[0] / 256;
  int B = out_size / 256;

  char* wsb = (char*)d_ws;
  float* wq_ws  = (float*)(wsb + 0);        // 1024 f32
  float* btot   = (float*)(wsb + 8192);     // 256 f32
  int*   starts = (int*)(wsb + 12288);      // B+1 int
  float* maskp  = (float*)(wsb + 45312);    // B f32
  __hip_bfloat16* mtt = (__hip_bfloat16*)(wsb + 78336);   // 256x1024 bf16
  __hip_bfloat16* Tp  = (__hip_bfloat16*)(wsb + 602624);  // B x 1024 bf16

  int nb_bounds = (N + 255) / 256;
  int nB = (B + 3) / 4;
  k_prep<<<dim3(4 + nb_bounds), dim3(256), 0, stream>>>(
      query, in_w, in_b, seg, wq_ws, starts, N, B);
  k_segattn<<<dim3(257 + nB), dim3(256), 0, stream>>>(
      emb, starts, wq_ws, maskp, Tp, B,
      in_w, in_b, out_w, out_b, up_w, up_b, mtt, btot);
  k_out<<<dim3(B / 64, 4), dim3(256), 0, stream>>>(Tp, mtt, btot, maskp, (float*)d_out);
}